// Round 1
// baseline (1716.904 us; speedup 1.0000x reference)
//
#include <hip/hip_runtime.h>
#include <stdint.h>

#define NB 8
#define NP 4096
#define NS 1024
#define NK 64
#define ND 64
#define CIN 67
#define NH 64
#define NCO 128

// ---------------- Kernel 1: farthest point sampling ----------------
// One block per batch. 256 threads, 16 points/thread in registers.
// Bit-exact fp32 (contract off) so argmax selections match the reference.
__global__ __launch_bounds__(256) void fps_kernel(const float* __restrict__ pos,
                                                  float* __restrict__ new_xyz)
{
#pragma clang fp contract(off)
    const int b    = blockIdx.x;
    const int tid  = threadIdx.x;
    const int lane = tid & 63;
    const int wv   = tid >> 6;

    __shared__ float sx[NP], sy[NP], sz[NP];
    __shared__ float rv[4];
    __shared__ int   ri[4];

    const float* p = pos + (size_t)b * NP * 3;
    for (int i = tid; i < NP; i += 256) {
        sx[i] = p[i * 3 + 0];
        sy[i] = p[i * 3 + 1];
        sz[i] = p[i * 3 + 2];
    }
    __syncthreads();

    float px[16], py[16], pz[16], md[16];
#pragma unroll
    for (int j = 0; j < 16; ++j) {
        int idx = tid * 16 + j;
        px[j] = sx[idx]; py[j] = sy[idx]; pz[j] = sz[idx];
        md[j] = 1e10f;
    }

    int last = 0;
    if (tid == 0) {
        float* o = new_xyz + (size_t)b * NS * 3;
        o[0] = sx[0]; o[1] = sy[0]; o[2] = sz[0];
    }

    for (int s = 1; s < NS; ++s) {
        const float lx = sx[last], ly = sy[last], lz = sz[last];
        float bv = -1.0f;
        int   bi = 0x7fffffff;
#pragma unroll
        for (int j = 0; j < 16; ++j) {
            float dx = px[j] - lx;
            float dy = py[j] - ly;
            float dz = pz[j] - lz;
            float d2 = dx * dx + dy * dy + dz * dz;   // contract(off): exact IEEE
            float m  = (md[j] < d2) ? md[j] : d2;     // jnp.minimum
            md[j] = m;
            if (m > bv) { bv = m; bi = tid * 16 + j; } // strict > keeps first idx
        }
        // wave argmax (tie -> smaller index, matches jnp.argmax)
#pragma unroll
        for (int off = 32; off >= 1; off >>= 1) {
            float ov = __shfl_xor(bv, off);
            int   oi = __shfl_xor(bi, off);
            if (ov > bv || (ov == bv && oi < bi)) { bv = ov; bi = oi; }
        }
        if (lane == 0) { rv[wv] = bv; ri[wv] = bi; }
        __syncthreads();
        float gbv = rv[0]; int gbi = ri[0];
#pragma unroll
        for (int w2 = 1; w2 < 4; ++w2) {
            float ov = rv[w2]; int oi = ri[w2];
            if (ov > gbv || (ov == gbv && oi < gbi)) { gbv = ov; gbi = oi; }
        }
        last = gbi;
        if (tid == 0) {
            float* o = new_xyz + ((size_t)b * NS + s) * 3;
            o[0] = sx[last]; o[1] = sy[last]; o[2] = sz[last];
        }
        __syncthreads();  // protect rv/ri for next step
    }
}

// ---------------- Kernel 2: ball query ----------------
// One wave per query: first-K-in-order neighbors within radius, -1 padded.
__global__ __launch_bounds__(256) void ballq_kernel(const float* __restrict__ pos,
                                                    const float* __restrict__ new_xyz,
                                                    int* __restrict__ ball_idx)
{
#pragma clang fp contract(off)
    const int lane = threadIdx.x & 63;
    const int q    = (blockIdx.x * 256 + threadIdx.x) >> 6;   // 0..NB*NS-1
    const int b    = q >> 10;

    const float* p  = pos + (size_t)b * NP * 3;
    const float  qx = new_xyz[q * 3 + 0];
    const float  qy = new_xyz[q * 3 + 1];
    const float  qz = new_xyz[q * 3 + 2];
    int* outp = ball_idx + (size_t)q * NK;

    int cnt = 0;
    for (int n0 = 0; n0 < NP; n0 += 64) {
        const int n = n0 + lane;
        float dx = qx - p[n * 3 + 0];
        float dy = qy - p[n * 3 + 1];
        float dz = qz - p[n * 3 + 2];
        float d2 = dx * dx + dy * dy + dz * dz;   // contract(off)
        bool within = d2 < 0.04f;                 // r^2, strict <
        unsigned long long m = __ballot(within);
        if (within) {
            int slot = cnt + __popcll(m & ((1ull << lane) - 1ull));
            if (slot < NK) outp[slot] = n;
        }
        cnt += (int)__popcll(m);
        if (cnt >= NK) break;
    }
    if (cnt < NK) {
        if (lane < NK - cnt) outp[cnt + lane] = -1;
    }
}

// ---------------- Kernel 3: gather + 3-layer MLP + masked max-pool ----------------
// One block (256 thr) per query. A^T and h^T in LDS (stride 68), weights staged
// per-layer into a reused LDS buffer. fp32 register tiles.
__global__ __launch_bounds__(256) void mlp_kernel(const float* __restrict__ x,
        const float* __restrict__ pos,
        const float* __restrict__ W1, const float* __restrict__ b1,
        const float* __restrict__ W2, const float* __restrict__ b2,
        const float* __restrict__ W3, const float* __restrict__ b3,
        const float* __restrict__ new_xyz, const int* __restrict__ ball_idx,
        float* __restrict__ out)
{
    const int bs   = blockIdx.x;      // b*NS + s
    const int b    = bs >> 10;
    const int tid  = threadIdx.x;
    const int lane = tid & 63;
    const int wv   = tid >> 6;

    __shared__ float At[CIN * 68];    // A^T / h2^T : [channel][k], stride 68
    __shared__ float Ht[NH * 68];     // h1^T
    __shared__ float Wl[NH * NCO];    // staged weights (max 64*128)
    __shared__ int   nbr[NK];
    __shared__ float qv[3];

    if (tid < NK) nbr[tid] = ball_idx[(size_t)bs * NK + tid];
    if (tid < 3)  qv[tid]  = new_xyz[(size_t)bs * 3 + tid];
    for (int t = tid; t < CIN * NH; t += 256) Wl[t] = W1[t];
    __syncthreads();

    // gather: wave wv loads rows k = wv*16 .. wv*16+15 (lane = channel)
    for (int m = 0; m < 16; ++m) {
        const int k = wv * 16 + m;
        int n = nbr[k];
        int nn = (n < 0) ? (NP - 1) : n;          // ref: points[-1] for padding
        At[(3 + lane) * 68 + k] = x[((size_t)b * NP + nn) * ND + lane];
        if (lane < 3)
            At[lane * 68 + k] = pos[((size_t)b * NP + nn) * 3 + lane] - qv[lane];
    }
    __syncthreads();

    const int kg = tid & 15;
    const int jg = tid >> 4;
    const int k0 = kg * 4;

    // ---- layer 1: h1 = relu(A @ W1 + b1), 64x64 ----
    {
        const int j0 = jg * 4;
        float acc[4][4];
#pragma unroll
        for (int jj = 0; jj < 4; ++jj) {
            float bb = b1[j0 + jj];
#pragma unroll
            for (int kk = 0; kk < 4; ++kk) acc[kk][jj] = bb;
        }
        for (int i = 0; i < CIN; ++i) {
            float4 av = *(const float4*)&At[i * 68 + k0];
            float4 wt = *(const float4*)&Wl[i * NH + j0];
            float a4[4] = {av.x, av.y, av.z, av.w};
            float w4[4] = {wt.x, wt.y, wt.z, wt.w};
#pragma unroll
            for (int kk = 0; kk < 4; ++kk)
#pragma unroll
                for (int jj = 0; jj < 4; ++jj)
                    acc[kk][jj] += a4[kk] * w4[jj];
        }
#pragma unroll
        for (int jj = 0; jj < 4; ++jj) {
            float4 v;
            v.x = fmaxf(acc[0][jj], 0.f); v.y = fmaxf(acc[1][jj], 0.f);
            v.z = fmaxf(acc[2][jj], 0.f); v.w = fmaxf(acc[3][jj], 0.f);
            *(float4*)&Ht[(j0 + jj) * 68 + k0] = v;
        }
    }
    __syncthreads();
    for (int t = tid; t < NH * NH; t += 256) Wl[t] = W2[t];
    __syncthreads();

    // ---- layer 2: h2 = relu(h1 @ W2 + b2), 64x64; write h2^T into At ----
    {
        const int j0 = jg * 4;
        float acc[4][4];
#pragma unroll
        for (int jj = 0; jj < 4; ++jj) {
            float bb = b2[j0 + jj];
#pragma unroll
            for (int kk = 0; kk < 4; ++kk) acc[kk][jj] = bb;
        }
        for (int i = 0; i < NH; ++i) {
            float4 av = *(const float4*)&Ht[i * 68 + k0];
            float4 wt = *(const float4*)&Wl[i * NH + j0];
            float a4[4] = {av.x, av.y, av.z, av.w};
            float w4[4] = {wt.x, wt.y, wt.z, wt.w};
#pragma unroll
            for (int kk = 0; kk < 4; ++kk)
#pragma unroll
                for (int jj = 0; jj < 4; ++jj)
                    acc[kk][jj] += a4[kk] * w4[jj];
        }
#pragma unroll
        for (int jj = 0; jj < 4; ++jj) {
            float4 v;
            v.x = fmaxf(acc[0][jj], 0.f); v.y = fmaxf(acc[1][jj], 0.f);
            v.z = fmaxf(acc[2][jj], 0.f); v.w = fmaxf(acc[3][jj], 0.f);
            *(float4*)&At[(j0 + jj) * 68 + k0] = v;
        }
    }
    __syncthreads();
    for (int t = tid; t < NH * NCO; t += 256) Wl[t] = W3[t];
    __syncthreads();

    // ---- layer 3: h3 = h2 @ W3 + b3 (64x128), mask, max over k ----
    {
        const int j0 = jg * 8;
        float acc[4][8];
#pragma unroll
        for (int jj = 0; jj < 8; ++jj) {
            float bb = b3[j0 + jj];
#pragma unroll
            for (int kk = 0; kk < 4; ++kk) acc[kk][jj] = bb;
        }
        for (int i = 0; i < NH; ++i) {
            float4 av = *(const float4*)&At[i * 68 + k0];
            float4 wa = *(const float4*)&Wl[i * NCO + j0];
            float4 wb = *(const float4*)&Wl[i * NCO + j0 + 4];
            float a4[4] = {av.x, av.y, av.z, av.w};
            float w8[8] = {wa.x, wa.y, wa.z, wa.w, wb.x, wb.y, wb.z, wb.w};
#pragma unroll
            for (int kk = 0; kk < 4; ++kk)
#pragma unroll
                for (int jj = 0; jj < 8; ++jj)
                    acc[kk][jj] += a4[kk] * w8[jj];
        }
        bool val[4];
#pragma unroll
        for (int kk = 0; kk < 4; ++kk) val[kk] = nbr[k0 + kk] >= 0;

        float pm[8];
#pragma unroll
        for (int jj = 0; jj < 8; ++jj) {
            float mv = val[0] ? acc[0][jj] : 0.0f;   // ref: hdn * mask, then max
#pragma unroll
            for (int kk = 1; kk < 4; ++kk) {
                float t = val[kk] ? acc[kk][jj] : 0.0f;
                mv = fmaxf(mv, t);
            }
            pm[jj] = mv;
        }
        // reduce over the 16 k-groups (lane bits 0..3)
#pragma unroll
        for (int off = 1; off < 16; off <<= 1) {
#pragma unroll
            for (int jj = 0; jj < 8; ++jj)
                pm[jj] = fmaxf(pm[jj], __shfl_xor(pm[jj], off));
        }
        if (kg == 0) {
#pragma unroll
            for (int jj = 0; jj < 8; ++jj)
                out[(size_t)bs * NCO + j0 + jj] = pm[jj];
        }
    }
}

extern "C" void kernel_launch(void* const* d_in, const int* in_sizes, int n_in,
                              void* d_out, int out_size, void* d_ws, size_t ws_size,
                              hipStream_t stream) {
    const float* x   = (const float*)d_in[0];
    const float* pos = (const float*)d_in[1];
    const float* W1  = (const float*)d_in[2];
    const float* b1  = (const float*)d_in[3];
    const float* W2  = (const float*)d_in[4];
    const float* b2  = (const float*)d_in[5];
    const float* W3  = (const float*)d_in[6];
    const float* b3  = (const float*)d_in[7];

    float* out0 = (float*)d_out;                       // [B,S,128]
    float* nxyz = out0 + (size_t)NB * NS * NCO;        // [B,S,3]
    int*   bidx = (int*)d_ws;                          // [B,S,K] = 2 MB

    fps_kernel<<<NB, 256, 0, stream>>>(pos, nxyz);
    ballq_kernel<<<(NB * NS) / 4, 256, 0, stream>>>(pos, nxyz, bidx);
    mlp_kernel<<<NB * NS, 256, 0, stream>>>(x, pos, W1, b1, W2, b2, W3, b3,
                                            nxyz, bidx, out0);
}

// Round 2
// 1279.052 us; speedup vs baseline: 1.3423x; 1.3423x over previous
//
#include <hip/hip_runtime.h>
#include <stdint.h>

#define NB 8
#define NP 4096
#define NS 1024
#define NK 64
#define ND 64
#define CIN 67
#define NH 64
#define NCO 128

#define FPS_T 512
#define PPT (NP / FPS_T)   // 8 points per thread

// ---------------- Kernel 1: farthest point sampling ----------------
// One block per batch, 512 threads, 8 points/thread in registers.
// Bit-exact fp32 (contract off) so argmax selections match the reference.
// Per step: local argmax (float cmp, idx ascending -> first-idx ties), pack
// (d2,~idx) into u64 once, 6-level wave shuffle-max, ONE barrier (parity
// double-buffered wave slots), redundant 8-way register tree combine.
__global__ __launch_bounds__(FPS_T) void fps_kernel(const float* __restrict__ pos,
                                                    float* __restrict__ new_xyz)
{
#pragma clang fp contract(off)
    const int b    = blockIdx.x;
    const int tid  = threadIdx.x;
    const int lane = tid & 63;
    const int wv   = tid >> 6;            // 0..7

    __shared__ float4 sp[NP];             // {x,y,z,0} per point, 64 KB
    __shared__ unsigned long long wbuf[2][8];

    const float* p = pos + (size_t)b * NP * 3;
    for (int i = tid; i < NP; i += FPS_T) {
        sp[i] = make_float4(p[i * 3 + 0], p[i * 3 + 1], p[i * 3 + 2], 0.0f);
    }
    __syncthreads();

    float px[PPT], py[PPT], pz[PPT], md[PPT];
#pragma unroll
    for (int j = 0; j < PPT; ++j) {
        float4 v = sp[tid * PPT + j];
        px[j] = v.x; py[j] = v.y; pz[j] = v.z;
        md[j] = 1e10f;
    }

    int last = 0;
    if (tid == 0) {
        float4 v = sp[0];
        float* o = new_xyz + (size_t)b * NS * 3;
        o[0] = v.x; o[1] = v.y; o[2] = v.z;
    }

    int par = 0;
    for (int s = 1; s < NS; ++s) {
        const float4 lp = sp[last];
        const float lx = lp.x, ly = lp.y, lz = lp.z;

        // local update + argmax (strict >, ascending idx => first-index ties)
        float bv = -1.0f;
        int   bi = 0;
#pragma unroll
        for (int j = 0; j < PPT; ++j) {
            float dx = px[j] - lx;
            float dy = py[j] - ly;
            float dz = pz[j] - lz;
            float d2 = dx * dx + dy * dy + dz * dz;   // contract(off): exact IEEE
            float m  = (md[j] < d2) ? md[j] : d2;     // jnp.minimum
            md[j] = m;
            if (m > bv) { bv = m; bi = tid * PPT + j; }
        }
        // pack: high=bits(d2) (all values >= 0 so bits are order-monotone),
        // low=~idx (max key => max d2, tie => min idx)
        unsigned long long bk =
            ((unsigned long long)__float_as_uint(bv) << 32) |
            (unsigned long long)(~(unsigned)bi);

        // wave max-reduce over packed keys
#pragma unroll
        for (int off = 32; off >= 1; off >>= 1) {
            unsigned long long ok = __shfl_xor(bk, off);
            if (ok > bk) bk = ok;
        }
        if (lane == 0) wbuf[par][wv] = bk;
        __syncthreads();

        // redundant 8-way tree combine (broadcast LDS reads)
        unsigned long long k0 = wbuf[par][0], k1 = wbuf[par][1];
        unsigned long long k2 = wbuf[par][2], k3 = wbuf[par][3];
        unsigned long long k4 = wbuf[par][4], k5 = wbuf[par][5];
        unsigned long long k6 = wbuf[par][6], k7 = wbuf[par][7];
        unsigned long long a0 = (k1 > k0) ? k1 : k0;
        unsigned long long a1 = (k3 > k2) ? k3 : k2;
        unsigned long long a2 = (k5 > k4) ? k5 : k4;
        unsigned long long a3 = (k7 > k6) ? k7 : k6;
        unsigned long long b0 = (a1 > a0) ? a1 : a0;
        unsigned long long b1 = (a3 > a2) ? a3 : a2;
        unsigned long long g  = (b1 > b0) ? b1 : b0;

        last = (int)(~(unsigned)g);
        if (tid == 0) {
            float4 v = sp[last];
            float* o = new_xyz + ((size_t)b * NS + s) * 3;
            o[0] = v.x; o[1] = v.y; o[2] = v.z;
        }
        par ^= 1;
    }
}

// ---------------- Kernel 2: ball query ----------------
// One wave per query: first-K-in-order neighbors within radius, -1 padded.
__global__ __launch_bounds__(256) void ballq_kernel(const float* __restrict__ pos,
                                                    const float* __restrict__ new_xyz,
                                                    int* __restrict__ ball_idx)
{
#pragma clang fp contract(off)
    const int lane = threadIdx.x & 63;
    const int q    = (blockIdx.x * 256 + threadIdx.x) >> 6;   // 0..NB*NS-1
    const int b    = q >> 10;

    const float* p  = pos + (size_t)b * NP * 3;
    const float  qx = new_xyz[q * 3 + 0];
    const float  qy = new_xyz[q * 3 + 1];
    const float  qz = new_xyz[q * 3 + 2];
    int* outp = ball_idx + (size_t)q * NK;

    int cnt = 0;
    for (int n0 = 0; n0 < NP; n0 += 64) {
        const int n = n0 + lane;
        float dx = qx - p[n * 3 + 0];
        float dy = qy - p[n * 3 + 1];
        float dz = qz - p[n * 3 + 2];
        float d2 = dx * dx + dy * dy + dz * dz;   // contract(off)
        bool within = d2 < 0.04f;                 // r^2, strict <
        unsigned long long m = __ballot(within);
        if (within) {
            int slot = cnt + __popcll(m & ((1ull << lane) - 1ull));
            if (slot < NK) outp[slot] = n;
        }
        cnt += (int)__popcll(m);
        if (cnt >= NK) break;
    }
    if (cnt < NK) {
        if (lane < NK - cnt) outp[cnt + lane] = -1;
    }
}

// ---------------- Kernel 3: gather + 3-layer MLP + masked max-pool ----------------
// One block (256 thr) per query. A^T and h^T in LDS (stride 68), weights staged
// per-layer into a reused LDS buffer. fp32 register tiles.
__global__ __launch_bounds__(256) void mlp_kernel(const float* __restrict__ x,
        const float* __restrict__ pos,
        const float* __restrict__ W1, const float* __restrict__ b1,
        const float* __restrict__ W2, const float* __restrict__ b2,
        const float* __restrict__ W3, const float* __restrict__ b3,
        const float* __restrict__ new_xyz, const int* __restrict__ ball_idx,
        float* __restrict__ out)
{
    const int bs   = blockIdx.x;      // b*NS + s
    const int b    = bs >> 10;
    const int tid  = threadIdx.x;
    const int lane = tid & 63;
    const int wv   = tid >> 6;

    __shared__ float At[CIN * 68];    // A^T / h2^T : [channel][k], stride 68
    __shared__ float Ht[NH * 68];     // h1^T
    __shared__ float Wl[NH * NCO];    // staged weights (max 64*128)
    __shared__ int   nbr[NK];
    __shared__ float qv[3];

    if (tid < NK) nbr[tid] = ball_idx[(size_t)bs * NK + tid];
    if (tid < 3)  qv[tid]  = new_xyz[(size_t)bs * 3 + tid];
    for (int t = tid; t < CIN * NH; t += 256) Wl[t] = W1[t];
    __syncthreads();

    // gather: wave wv loads rows k = wv*16 .. wv*16+15 (lane = channel)
    for (int m = 0; m < 16; ++m) {
        const int k = wv * 16 + m;
        int n = nbr[k];
        int nn = (n < 0) ? (NP - 1) : n;          // ref: points[-1] for padding
        At[(3 + lane) * 68 + k] = x[((size_t)b * NP + nn) * ND + lane];
        if (lane < 3)
            At[lane * 68 + k] = pos[((size_t)b * NP + nn) * 3 + lane] - qv[lane];
    }
    __syncthreads();

    const int kg = tid & 15;
    const int jg = tid >> 4;
    const int k0 = kg * 4;

    // ---- layer 1: h1 = relu(A @ W1 + b1), 64x64 ----
    {
        const int j0 = jg * 4;
        float acc[4][4];
#pragma unroll
        for (int jj = 0; jj < 4; ++jj) {
            float bb = b1[j0 + jj];
#pragma unroll
            for (int kk = 0; kk < 4; ++kk) acc[kk][jj] = bb;
        }
        for (int i = 0; i < CIN; ++i) {
            float4 av = *(const float4*)&At[i * 68 + k0];
            float4 wt = *(const float4*)&Wl[i * NH + j0];
            float a4[4] = {av.x, av.y, av.z, av.w};
            float w4[4] = {wt.x, wt.y, wt.z, wt.w};
#pragma unroll
            for (int kk = 0; kk < 4; ++kk)
#pragma unroll
                for (int jj = 0; jj < 4; ++jj)
                    acc[kk][jj] += a4[kk] * w4[jj];
        }
#pragma unroll
        for (int jj = 0; jj < 4; ++jj) {
            float4 v;
            v.x = fmaxf(acc[0][jj], 0.f); v.y = fmaxf(acc[1][jj], 0.f);
            v.z = fmaxf(acc[2][jj], 0.f); v.w = fmaxf(acc[3][jj], 0.f);
            *(float4*)&Ht[(j0 + jj) * 68 + k0] = v;
        }
    }
    __syncthreads();
    for (int t = tid; t < NH * NH; t += 256) Wl[t] = W2[t];
    __syncthreads();

    // ---- layer 2: h2 = relu(h1 @ W2 + b2), 64x64; write h2^T into At ----
    {
        const int j0 = jg * 4;
        float acc[4][4];
#pragma unroll
        for (int jj = 0; jj < 4; ++jj) {
            float bb = b2[j0 + jj];
#pragma unroll
            for (int kk = 0; kk < 4; ++kk) acc[kk][jj] = bb;
        }
        for (int i = 0; i < NH; ++i) {
            float4 av = *(const float4*)&Ht[i * 68 + k0];
            float4 wt = *(const float4*)&Wl[i * NH + j0];
            float a4[4] = {av.x, av.y, av.z, av.w};
            float w4[4] = {wt.x, wt.y, wt.z, wt.w};
#pragma unroll
            for (int kk = 0; kk < 4; ++kk)
#pragma unroll
                for (int jj = 0; jj < 4; ++jj)
                    acc[kk][jj] += a4[kk] * w4[jj];
        }
#pragma unroll
        for (int jj = 0; jj < 4; ++jj) {
            float4 v;
            v.x = fmaxf(acc[0][jj], 0.f); v.y = fmaxf(acc[1][jj], 0.f);
            v.z = fmaxf(acc[2][jj], 0.f); v.w = fmaxf(acc[3][jj], 0.f);
            *(float4*)&At[(j0 + jj) * 68 + k0] = v;
        }
    }
    __syncthreads();
    for (int t = tid; t < NH * NCO; t += 256) Wl[t] = W3[t];
    __syncthreads();

    // ---- layer 3: h3 = h2 @ W3 + b3 (64x128), mask, max over k ----
    {
        const int j0 = jg * 8;
        float acc[4][8];
#pragma unroll
        for (int jj = 0; jj < 8; ++jj) {
            float bb = b3[j0 + jj];
#pragma unroll
            for (int kk = 0; kk < 4; ++kk) acc[kk][jj] = bb;
        }
        for (int i = 0; i < NH; ++i) {
            float4 av = *(const float4*)&At[i * 68 + k0];
            float4 wa = *(const float4*)&Wl[i * NCO + j0];
            float4 wb = *(const float4*)&Wl[i * NCO + j0 + 4];
            float a4[4] = {av.x, av.y, av.z, av.w};
            float w8[8] = {wa.x, wa.y, wa.z, wa.w, wb.x, wb.y, wb.z, wb.w};
#pragma unroll
            for (int kk = 0; kk < 4; ++kk)
#pragma unroll
                for (int jj = 0; jj < 8; ++jj)
                    acc[kk][jj] += a4[kk] * w8[jj];
        }
        bool val[4];
#pragma unroll
        for (int kk = 0; kk < 4; ++kk) val[kk] = nbr[k0 + kk] >= 0;

        float pm[8];
#pragma unroll
        for (int jj = 0; jj < 8; ++jj) {
            float mv = val[0] ? acc[0][jj] : 0.0f;   // ref: hdn * mask, then max
#pragma unroll
            for (int kk = 1; kk < 4; ++kk) {
                float t = val[kk] ? acc[kk][jj] : 0.0f;
                mv = fmaxf(mv, t);
            }
            pm[jj] = mv;
        }
        // reduce over the 16 k-groups (lane bits 0..3)
#pragma unroll
        for (int off = 1; off < 16; off <<= 1) {
#pragma unroll
            for (int jj = 0; jj < 8; ++jj)
                pm[jj] = fmaxf(pm[jj], __shfl_xor(pm[jj], off));
        }
        if (kg == 0) {
#pragma unroll
            for (int jj = 0; jj < 8; ++jj)
                out[(size_t)bs * NCO + j0 + jj] = pm[jj];
        }
    }
}

extern "C" void kernel_launch(void* const* d_in, const int* in_sizes, int n_in,
                              void* d_out, int out_size, void* d_ws, size_t ws_size,
                              hipStream_t stream) {
    const float* x   = (const float*)d_in[0];
    const float* pos = (const float*)d_in[1];
    const float* W1  = (const float*)d_in[2];
    const float* b1  = (const float*)d_in[3];
    const float* W2  = (const float*)d_in[4];
    const float* b2  = (const float*)d_in[5];
    const float* W3  = (const float*)d_in[6];
    const float* b3  = (const float*)d_in[7];

    float* out0 = (float*)d_out;                       // [B,S,128]
    float* nxyz = out0 + (size_t)NB * NS * NCO;        // [B,S,3]
    int*   bidx = (int*)d_ws;                          // [B,S,K] = 2 MB

    fps_kernel<<<NB, FPS_T, 0, stream>>>(pos, nxyz);
    ballq_kernel<<<(NB * NS) / 4, 256, 0, stream>>>(pos, nxyz, bidx);
    mlp_kernel<<<NB * NS, 256, 0, stream>>>(x, pos, W1, b1, W2, b2, W3, b3,
                                            nxyz, bidx, out0);
}

// Round 3
// 1110.849 us; speedup vs baseline: 1.5456x; 1.1514x over previous
//
#include <hip/hip_runtime.h>
#include <stdint.h>

#define NB 8
#define NP 4096
#define NS 1024
#define NK 64
#define ND 64
#define CIN 67
#define NH 64
#define NCO 128

#define FPS_T 512
#define PPT (NP / FPS_T)   // 8 points per thread

// DPP move helper (ctrl must be compile-time constant)
template <int CTRL>
__device__ __forceinline__ float dpp_mov_f32(float x) {
    return __int_as_float(__builtin_amdgcn_update_dpp(
        0, __float_as_int(x), CTRL, 0xf, 0xf, true));
}

// ---------------- Kernel 1: farthest point sampling ----------------
// One block per batch, 512 threads, 8 points/thread in registers.
// Bit-exact fp32 (contract off) so argmax selections match the reference.
// Per step: local update+argmax; wave value-max via DPP (row_shr + row_bcast,
// result in lane 63); winner index via ballot+ctz+readlane (lane order ==
// global index order -> first matching lane = smallest index, exact argmax
// ties); cross-wave via packed u64 keys in parity-double-buffered LDS slots
// (ONE barrier/step), redundant 8-way register tree.
__global__ __launch_bounds__(FPS_T) void fps_kernel(const float* __restrict__ pos,
                                                    float* __restrict__ new_xyz)
{
#pragma clang fp contract(off)
    const int b    = blockIdx.x;
    const int tid  = threadIdx.x;
    const int lane = tid & 63;
    const int wv   = tid >> 6;            // 0..7

    __shared__ float4 sp[NP];             // {x,y,z,0} per point, 64 KB
    __shared__ alignas(16) unsigned long long wbuf[2][8];

    const float* p = pos + (size_t)b * NP * 3;
    for (int i = tid; i < NP; i += FPS_T) {
        sp[i] = make_float4(p[i * 3 + 0], p[i * 3 + 1], p[i * 3 + 2], 0.0f);
    }
    __syncthreads();

    float px[PPT], py[PPT], pz[PPT], md[PPT];
#pragma unroll
    for (int j = 0; j < PPT; ++j) {
        float4 v = sp[tid * PPT + j];
        px[j] = v.x; py[j] = v.y; pz[j] = v.z;
        md[j] = 1e10f;
    }

    int last = 0;
    if (tid == 0) {
        float4 v = sp[0];
        float* o = new_xyz + (size_t)b * NS * 3;
        o[0] = v.x; o[1] = v.y; o[2] = v.z;
    }

    int par = 0;
    for (int s = 1; s < NS; ++s) {
        const float4 lp = sp[last];
        const float lx = lp.x, ly = lp.y, lz = lp.z;

        // local update + argmax (strict >, ascending idx => first-index ties).
        // all md >= 0, so bv=0 init is exact (if local max==0, every md==0 and
        // the first owned index is the correct first-occurrence argmax).
        float bv = 0.0f;
        int   bi = tid * PPT;
#pragma unroll
        for (int j = 0; j < PPT; ++j) {
            float dx = px[j] - lx;
            float dy = py[j] - ly;
            float dz = pz[j] - lz;
            float d2 = dx * dx + dy * dy + dz * dz;   // contract(off): exact IEEE
            float m  = (md[j] < d2) ? md[j] : d2;     // jnp.minimum
            md[j] = m;
            if (m > bv) { bv = m; bi = tid * PPT + j; }
        }

        // wave max of bv via DPP (values >= 0 so zero-fill is identity).
        // final full-wave max lands in lane 63.
        float r = bv;
        r = fmaxf(r, dpp_mov_f32<0x111>(r));   // row_shr:1
        r = fmaxf(r, dpp_mov_f32<0x112>(r));   // row_shr:2
        r = fmaxf(r, dpp_mov_f32<0x114>(r));   // row_shr:4
        r = fmaxf(r, dpp_mov_f32<0x118>(r));   // row_shr:8
        r = fmaxf(r, dpp_mov_f32<0x142>(r));   // row_bcast:15
        r = fmaxf(r, dpp_mov_f32<0x143>(r));   // row_bcast:31
        const float gmax = __int_as_float(
            __builtin_amdgcn_readlane(__float_as_int(r), 63));

        // first lane achieving gmax = smallest achieving index in this wave
        unsigned long long mk = __ballot(bv == gmax);
        int wl = (int)__builtin_ctzll(mk);
        int bw = __builtin_amdgcn_readlane(bi, wl);

        if (lane == 0) {
            wbuf[par][wv] =
                ((unsigned long long)__float_as_uint(gmax) << 32) |
                (unsigned long long)(~(unsigned)bw);
        }
        __syncthreads();

        // redundant 8-way tree combine (broadcast b128 LDS reads)
        const ulonglong2* wb = (const ulonglong2*)wbuf[par];
        ulonglong2 q0 = wb[0], q1 = wb[1], q2 = wb[2], q3 = wb[3];
        unsigned long long a0 = (q0.y > q0.x) ? q0.y : q0.x;
        unsigned long long a1 = (q1.y > q1.x) ? q1.y : q1.x;
        unsigned long long a2 = (q2.y > q2.x) ? q2.y : q2.x;
        unsigned long long a3 = (q3.y > q3.x) ? q3.y : q3.x;
        unsigned long long b0 = (a1 > a0) ? a1 : a0;
        unsigned long long b1 = (a3 > a2) ? a3 : a2;
        unsigned long long g  = (b1 > b0) ? b1 : b0;

        last = (int)(~(unsigned)g);
        if (tid == 0) {
            float4 v = sp[last];
            float* o = new_xyz + ((size_t)b * NS + s) * 3;
            o[0] = v.x; o[1] = v.y; o[2] = v.z;
        }
        par ^= 1;
    }
}

// ---------------- Kernel 2: ball query ----------------
// One wave per query: first-K-in-order neighbors within radius, -1 padded.
__global__ __launch_bounds__(256) void ballq_kernel(const float* __restrict__ pos,
                                                    const float* __restrict__ new_xyz,
                                                    int* __restrict__ ball_idx)
{
#pragma clang fp contract(off)
    const int lane = threadIdx.x & 63;
    const int q    = (blockIdx.x * 256 + threadIdx.x) >> 6;   // 0..NB*NS-1
    const int b    = q >> 10;

    const float* p  = pos + (size_t)b * NP * 3;
    const float  qx = new_xyz[q * 3 + 0];
    const float  qy = new_xyz[q * 3 + 1];
    const float  qz = new_xyz[q * 3 + 2];
    int* outp = ball_idx + (size_t)q * NK;

    int cnt = 0;
    for (int n0 = 0; n0 < NP; n0 += 64) {
        const int n = n0 + lane;
        float dx = qx - p[n * 3 + 0];
        float dy = qy - p[n * 3 + 1];
        float dz = qz - p[n * 3 + 2];
        float d2 = dx * dx + dy * dy + dz * dz;   // contract(off)
        bool within = d2 < 0.04f;                 // r^2, strict <
        unsigned long long m = __ballot(within);
        if (within) {
            int slot = cnt + __popcll(m & ((1ull << lane) - 1ull));
            if (slot < NK) outp[slot] = n;
        }
        cnt += (int)__popcll(m);
        if (cnt >= NK) break;
    }
    if (cnt < NK) {
        if (lane < NK - cnt) outp[cnt + lane] = -1;
    }
}

// ---------------- Kernel 3: gather + 3-layer MLP + masked max-pool ----------------
// One block (256 thr) per query. A^T and h^T in LDS (stride 68), weights staged
// per-layer into a reused LDS buffer. fp32 register tiles.
__global__ __launch_bounds__(256) void mlp_kernel(const float* __restrict__ x,
        const float* __restrict__ pos,
        const float* __restrict__ W1, const float* __restrict__ b1,
        const float* __restrict__ W2, const float* __restrict__ b2,
        const float* __restrict__ W3, const float* __restrict__ b3,
        const float* __restrict__ new_xyz, const int* __restrict__ ball_idx,
        float* __restrict__ out)
{
    const int bs   = blockIdx.x;      // b*NS + s
    const int b    = bs >> 10;
    const int tid  = threadIdx.x;
    const int lane = tid & 63;
    const int wv   = tid >> 6;

    __shared__ float At[CIN * 68];    // A^T / h2^T : [channel][k], stride 68
    __shared__ float Ht[NH * 68];     // h1^T
    __shared__ float Wl[NH * NCO];    // staged weights (max 64*128)
    __shared__ int   nbr[NK];
    __shared__ float qv[3];

    if (tid < NK) nbr[tid] = ball_idx[(size_t)bs * NK + tid];
    if (tid < 3)  qv[tid]  = new_xyz[(size_t)bs * 3 + tid];
    for (int t = tid; t < CIN * NH; t += 256) Wl[t] = W1[t];
    __syncthreads();

    // gather: wave wv loads rows k = wv*16 .. wv*16+15 (lane = channel)
    for (int m = 0; m < 16; ++m) {
        const int k = wv * 16 + m;
        int n = nbr[k];
        int nn = (n < 0) ? (NP - 1) : n;          // ref: points[-1] for padding
        At[(3 + lane) * 68 + k] = x[((size_t)b * NP + nn) * ND + lane];
        if (lane < 3)
            At[lane * 68 + k] = pos[((size_t)b * NP + nn) * 3 + lane] - qv[lane];
    }
    __syncthreads();

    const int kg = tid & 15;
    const int jg = tid >> 4;
    const int k0 = kg * 4;

    // ---- layer 1: h1 = relu(A @ W1 + b1), 64x64 ----
    {
        const int j0 = jg * 4;
        float acc[4][4];
#pragma unroll
        for (int jj = 0; jj < 4; ++jj) {
            float bb = b1[j0 + jj];
#pragma unroll
            for (int kk = 0; kk < 4; ++kk) acc[kk][jj] = bb;
        }
        for (int i = 0; i < CIN; ++i) {
            float4 av = *(const float4*)&At[i * 68 + k0];
            float4 wt = *(const float4*)&Wl[i * NH + j0];
            float a4[4] = {av.x, av.y, av.z, av.w};
            float w4[4] = {wt.x, wt.y, wt.z, wt.w};
#pragma unroll
            for (int kk = 0; kk < 4; ++kk)
#pragma unroll
                for (int jj = 0; jj < 4; ++jj)
                    acc[kk][jj] += a4[kk] * w4[jj];
        }
#pragma unroll
        for (int jj = 0; jj < 4; ++jj) {
            float4 v;
            v.x = fmaxf(acc[0][jj], 0.f); v.y = fmaxf(acc[1][jj], 0.f);
            v.z = fmaxf(acc[2][jj], 0.f); v.w = fmaxf(acc[3][jj], 0.f);
            *(float4*)&Ht[(j0 + jj) * 68 + k0] = v;
        }
    }
    __syncthreads();
    for (int t = tid; t < NH * NH; t += 256) Wl[t] = W2[t];
    __syncthreads();

    // ---- layer 2: h2 = relu(h1 @ W2 + b2), 64x64; write h2^T into At ----
    {
        const int j0 = jg * 4;
        float acc[4][4];
#pragma unroll
        for (int jj = 0; jj < 4; ++jj) {
            float bb = b2[j0 + jj];
#pragma unroll
            for (int kk = 0; kk < 4; ++kk) acc[kk][jj] = bb;
        }
        for (int i = 0; i < NH; ++i) {
            float4 av = *(const float4*)&Ht[i * 68 + k0];
            float4 wt = *(const float4*)&Wl[i * NH + j0];
            float a4[4] = {av.x, av.y, av.z, av.w};
            float w4[4] = {wt.x, wt.y, wt.z, wt.w};
#pragma unroll
            for (int kk = 0; kk < 4; ++kk)
#pragma unroll
                for (int jj = 0; jj < 4; ++jj)
                    acc[kk][jj] += a4[kk] * w4[jj];
        }
#pragma unroll
        for (int jj = 0; jj < 4; ++jj) {
            float4 v;
            v.x = fmaxf(acc[0][jj], 0.f); v.y = fmaxf(acc[1][jj], 0.f);
            v.z = fmaxf(acc[2][jj], 0.f); v.w = fmaxf(acc[3][jj], 0.f);
            *(float4*)&At[(j0 + jj) * 68 + k0] = v;
        }
    }
    __syncthreads();
    for (int t = tid; t < NH * NCO; t += 256) Wl[t] = W3[t];
    __syncthreads();

    // ---- layer 3: h3 = h2 @ W3 + b3 (64x128), mask, max over k ----
    {
        const int j0 = jg * 8;
        float acc[4][8];
#pragma unroll
        for (int jj = 0; jj < 8; ++jj) {
            float bb = b3[j0 + jj];
#pragma unroll
            for (int kk = 0; kk < 4; ++kk) acc[kk][jj] = bb;
        }
        for (int i = 0; i < NH; ++i) {
            float4 av = *(const float4*)&At[i * 68 + k0];
            float4 wa = *(const float4*)&Wl[i * NCO + j0];
            float4 wb = *(const float4*)&Wl[i * NCO + j0 + 4];
            float a4[4] = {av.x, av.y, av.z, av.w};
            float w8[8] = {wa.x, wa.y, wa.z, wa.w, wb.x, wb.y, wb.z, wb.w};
#pragma unroll
            for (int kk = 0; kk < 4; ++kk)
#pragma unroll
                for (int jj = 0; jj < 8; ++jj)
                    acc[kk][jj] += a4[kk] * w8[jj];
        }
        bool val[4];
#pragma unroll
        for (int kk = 0; kk < 4; ++kk) val[kk] = nbr[k0 + kk] >= 0;

        float pm[8];
#pragma unroll
        for (int jj = 0; jj < 8; ++jj) {
            float mv = val[0] ? acc[0][jj] : 0.0f;   // ref: hdn * mask, then max
#pragma unroll
            for (int kk = 1; kk < 4; ++kk) {
                float t = val[kk] ? acc[kk][jj] : 0.0f;
                mv = fmaxf(mv, t);
            }
            pm[jj] = mv;
        }
        // reduce over the 16 k-groups (lane bits 0..3)
#pragma unroll
        for (int off = 1; off < 16; off <<= 1) {
#pragma unroll
            for (int jj = 0; jj < 8; ++jj)
                pm[jj] = fmaxf(pm[jj], __shfl_xor(pm[jj], off));
        }
        if (kg == 0) {
#pragma unroll
            for (int jj = 0; jj < 8; ++jj)
                out[(size_t)bs * NCO + j0 + jj] = pm[jj];
        }
    }
}

extern "C" void kernel_launch(void* const* d_in, const int* in_sizes, int n_in,
                              void* d_out, int out_size, void* d_ws, size_t ws_size,
                              hipStream_t stream) {
    const float* x   = (const float*)d_in[0];
    const float* pos = (const float*)d_in[1];
    const float* W1  = (const float*)d_in[2];
    const float* b1  = (const float*)d_in[3];
    const float* W2  = (const float*)d_in[4];
    const float* b2  = (const float*)d_in[5];
    const float* W3  = (const float*)d_in[6];
    const float* b3  = (const float*)d_in[7];

    float* out0 = (float*)d_out;                       // [B,S,128]
    float* nxyz = out0 + (size_t)NB * NS * NCO;        // [B,S,3]
    int*   bidx = (int*)d_ws;                          // [B,S,K] = 2 MB

    fps_kernel<<<NB, FPS_T, 0, stream>>>(pos, nxyz);
    ballq_kernel<<<(NB * NS) / 4, 256, 0, stream>>>(pos, nxyz, bidx);
    mlp_kernel<<<NB * NS, 256, 0, stream>>>(x, pos, W1, b1, W2, b2, W3, b3,
                                            nxyz, bidx, out0);
}

// Round 4
// 903.006 us; speedup vs baseline: 1.9013x; 1.2302x over previous
//
#include <hip/hip_runtime.h>
#include <stdint.h>

#define NB 8
#define NP 4096
#define NS 1024
#define NK 64
#define ND 64
#define NH 64
#define NCO 128

#define FPS_T 512
#define PPT (NP / FPS_T)   // 8 points per thread

// padded K strides (in halves) for conflict-free b128 LDS access
#define K1P 104            // layer1 K: 64 x-ch + 3 xyz + zeros to 96, padded to 104
#define K2P 72             // layer2/3 K: 64, padded to 72

typedef _Float16 half8v __attribute__((ext_vector_type(8)));
typedef _Float16 half4v __attribute__((ext_vector_type(4)));
typedef _Float16 half2v __attribute__((ext_vector_type(2)));
typedef float    floatx4 __attribute__((ext_vector_type(4)));

// DPP move helper (ctrl must be compile-time constant)
template <int CTRL>
__device__ __forceinline__ float dpp_mov_f32(float x) {
    return __int_as_float(__builtin_amdgcn_update_dpp(
        0, __float_as_int(x), CTRL, 0xf, 0xf, true));
}

// ---------------- Kernel 0: weight transpose + f16 convert ----------------
// wt layout (halves): [0)      W1t[64][104]: k<64 -> W1[(3+k)*64+j] (x chans),
//                              k=64..66 -> W1[(k-64)*64+j] (xyz), else 0
//                     [6656)   W2t[64][72]:  k<64 -> W2[k*64+r], else 0
//                     [11264)  W3t[128][72]: k<64 -> W3[k*128+r], else 0
__global__ __launch_bounds__(64) void wt_kernel(const float* __restrict__ W1,
                                                const float* __restrict__ W2,
                                                const float* __restrict__ W3,
                                                _Float16* __restrict__ wt)
{
    const int j = blockIdx.x;
    const int t = threadIdx.x;
    if (j < 64) {
        for (int k = t; k < K1P; k += 64) {
            float v = 0.f;
            if (k < 64)       v = W1[(3 + k) * 64 + j];
            else if (k < 67)  v = W1[(k - 64) * 64 + j];
            wt[j * K1P + k] = (_Float16)v;
        }
    } else if (j < 128) {
        const int r = j - 64;
        for (int k = t; k < K2P; k += 64) {
            float v = (k < 64) ? W2[k * 64 + r] : 0.f;
            wt[6656 + r * K2P + k] = (_Float16)v;
        }
    } else {
        const int r = j - 128;
        for (int k = t; k < K2P; k += 64) {
            float v = (k < 64) ? W3[k * 128 + r] : 0.f;
            wt[11264 + r * K2P + k] = (_Float16)v;
        }
    }
}

// ---------------- Kernel 1: farthest point sampling (bit-exact, unchanged) ----
__global__ __launch_bounds__(FPS_T) void fps_kernel(const float* __restrict__ pos,
                                                    float* __restrict__ new_xyz)
{
#pragma clang fp contract(off)
    const int b    = blockIdx.x;
    const int tid  = threadIdx.x;
    const int lane = tid & 63;
    const int wv   = tid >> 6;            // 0..7

    __shared__ float4 sp[NP];             // {x,y,z,0} per point, 64 KB
    __shared__ alignas(16) unsigned long long wbuf[2][8];

    const float* p = pos + (size_t)b * NP * 3;
    for (int i = tid; i < NP; i += FPS_T) {
        sp[i] = make_float4(p[i * 3 + 0], p[i * 3 + 1], p[i * 3 + 2], 0.0f);
    }
    __syncthreads();

    float px[PPT], py[PPT], pz[PPT], md[PPT];
#pragma unroll
    for (int j = 0; j < PPT; ++j) {
        float4 v = sp[tid * PPT + j];
        px[j] = v.x; py[j] = v.y; pz[j] = v.z;
        md[j] = 1e10f;
    }

    int last = 0;
    if (tid == 0) {
        float4 v = sp[0];
        float* o = new_xyz + (size_t)b * NS * 3;
        o[0] = v.x; o[1] = v.y; o[2] = v.z;
    }

    int par = 0;
    for (int s = 1; s < NS; ++s) {
        const float4 lp = sp[last];
        const float lx = lp.x, ly = lp.y, lz = lp.z;

        float bv = 0.0f;
        int   bi = tid * PPT;
#pragma unroll
        for (int j = 0; j < PPT; ++j) {
            float dx = px[j] - lx;
            float dy = py[j] - ly;
            float dz = pz[j] - lz;
            float d2 = dx * dx + dy * dy + dz * dz;   // contract(off): exact IEEE
            float m  = (md[j] < d2) ? md[j] : d2;     // jnp.minimum
            md[j] = m;
            if (m > bv) { bv = m; bi = tid * PPT + j; }
        }

        float r = bv;
        r = fmaxf(r, dpp_mov_f32<0x111>(r));   // row_shr:1
        r = fmaxf(r, dpp_mov_f32<0x112>(r));   // row_shr:2
        r = fmaxf(r, dpp_mov_f32<0x114>(r));   // row_shr:4
        r = fmaxf(r, dpp_mov_f32<0x118>(r));   // row_shr:8
        r = fmaxf(r, dpp_mov_f32<0x142>(r));   // row_bcast:15
        r = fmaxf(r, dpp_mov_f32<0x143>(r));   // row_bcast:31
        const float gmax = __int_as_float(
            __builtin_amdgcn_readlane(__float_as_int(r), 63));

        unsigned long long mk = __ballot(bv == gmax);
        int wl = (int)__builtin_ctzll(mk);
        int bw = __builtin_amdgcn_readlane(bi, wl);

        if (lane == 0) {
            wbuf[par][wv] =
                ((unsigned long long)__float_as_uint(gmax) << 32) |
                (unsigned long long)(~(unsigned)bw);
        }
        __syncthreads();

        const ulonglong2* wb = (const ulonglong2*)wbuf[par];
        ulonglong2 q0 = wb[0], q1 = wb[1], q2 = wb[2], q3 = wb[3];
        unsigned long long a0 = (q0.y > q0.x) ? q0.y : q0.x;
        unsigned long long a1 = (q1.y > q1.x) ? q1.y : q1.x;
        unsigned long long a2 = (q2.y > q2.x) ? q2.y : q2.x;
        unsigned long long a3 = (q3.y > q3.x) ? q3.y : q3.x;
        unsigned long long b0 = (a1 > a0) ? a1 : a0;
        unsigned long long b1 = (a3 > a2) ? a3 : a2;
        unsigned long long g  = (b1 > b0) ? b1 : b0;

        last = (int)(~(unsigned)g);
        if (tid == 0) {
            float4 v = sp[last];
            float* o = new_xyz + ((size_t)b * NS + s) * 3;
            o[0] = v.x; o[1] = v.y; o[2] = v.z;
        }
        par ^= 1;
    }
}

// ---------------- Kernel 2: ball query (int16 output) ----------------
__global__ __launch_bounds__(256) void ballq_kernel(const float* __restrict__ pos,
                                                    const float* __restrict__ new_xyz,
                                                    short* __restrict__ ball_idx)
{
#pragma clang fp contract(off)
    const int lane = threadIdx.x & 63;
    const int q    = (blockIdx.x * 256 + threadIdx.x) >> 6;   // 0..NB*NS-1
    const int b    = q >> 10;

    const float* p  = pos + (size_t)b * NP * 3;
    const float  qx = new_xyz[q * 3 + 0];
    const float  qy = new_xyz[q * 3 + 1];
    const float  qz = new_xyz[q * 3 + 2];
    short* outp = ball_idx + (size_t)q * NK;

    int cnt = 0;
    for (int n0 = 0; n0 < NP; n0 += 64) {
        const int n = n0 + lane;
        float dx = qx - p[n * 3 + 0];
        float dy = qy - p[n * 3 + 1];
        float dz = qz - p[n * 3 + 2];
        float d2 = dx * dx + dy * dy + dz * dz;   // contract(off)
        bool within = d2 < 0.04f;                 // r^2, strict <
        unsigned long long m = __ballot(within);
        if (within) {
            int slot = cnt + __popcll(m & ((1ull << lane) - 1ull));
            if (slot < NK) outp[slot] = (short)n;
        }
        cnt += (int)__popcll(m);
        if (cnt >= NK) break;
    }
    if (cnt < NK) {
        if (lane < NK - cnt) outp[cnt + lane] = (short)-1;
    }
}

// ---------------- Kernel 3: gather + f16-MFMA MLP + masked max-pool ----------
// One block (4 waves) per query; wave wv owns neighbors wv*16..wv*16+15.
// Transposed formulation: every layer computes h^T = W^T * hprev^T, so the
// MFMA C/D col (= lane&15) is always the neighbor dim and layer chaining is a
// cheap packed-b64 LDS round-trip (A-layout: A[m=lane&15][k=quad*8+j];
// C/D: col=lane&15, row=quad*4+reg).
__global__ __launch_bounds__(256) void mlp_kernel(const float* __restrict__ x,
        const float* __restrict__ pos,
        const float* __restrict__ b1, const float* __restrict__ b2,
        const float* __restrict__ b3,
        const float* __restrict__ new_xyz, const short* __restrict__ ball_idx,
        const _Float16* __restrict__ wt,
        float* __restrict__ out)
{
    const int bs   = blockIdx.x;      // b*NS + s
    const int b    = bs >> 10;
    const int tid  = threadIdx.x;
    const int lane = tid & 63;
    const int wv   = tid >> 6;
    const int q    = lane >> 4;       // quad
    const int c    = lane & 15;       // col within MFMA tile

    __shared__ alignas(16) _Float16 G [64 * K1P];   // gathered A^T-ish: [nbr][k]
    __shared__ alignas(16) _Float16 sW[20480];      // W1t | W2t | W3t (f16)
    __shared__ alignas(16) _Float16 H1[64 * K2P];   // h1^T as [nbr][ch]
    __shared__ alignas(16) _Float16 H2[64 * K2P];   // h2^T as [nbr][ch]
    __shared__ alignas(16) float    CW[4 * NCO];    // per-wave pooled partials
    __shared__ alignas(16) float    Lb[256];        // b1|b2|b3 staged
    __shared__ short nbr_s[NK];
    __shared__ float qv[3];

    if (tid < NK)  nbr_s[tid] = ball_idx[(size_t)bs * NK + tid];
    if (tid < 3)   qv[tid]    = new_xyz[(size_t)bs * 3 + tid];
    if (tid < 64) { Lb[tid] = b1[tid]; Lb[64 + tid] = b2[tid]; }
    if (tid < 128) Lb[128 + tid] = b3[tid];
    // zero G (832 half8 stores)
    {
        half8v z = {};
        for (int i = tid; i < (64 * K1P) / 8; i += 256) ((half8v*)G)[i] = z;
    }
    // stage weights: 20480 halves = 2560 b128 copies
    for (int i = tid; i < 2560; i += 256) ((half8v*)sW)[i] = ((const half8v*)wt)[i];
    __syncthreads();   // nbr_s, qv, G zeros visible

    // gather: thread t -> neighbor t>>2, x-channel quarter t&3
    {
        const int ni = tid >> 2;
        const int p4 = tid & 3;
        const int n  = nbr_s[ni];
        const int nn = (n < 0) ? (NP - 1) : n;
        const float* xr = x + ((size_t)b * NP + nn) * ND + p4 * 16;
#pragma unroll
        for (int i = 0; i < 4; ++i) {
            float4 v = *(const float4*)(xr + 4 * i);
            half4v h;
            h[0] = (_Float16)v.x; h[1] = (_Float16)v.y;
            h[2] = (_Float16)v.z; h[3] = (_Float16)v.w;
            *(half4v*)&G[ni * K1P + p4 * 16 + 4 * i] = h;
        }
        if (p4 == 0) {
            const float* pr = pos + (size_t)(b * NP + nn) * 3;
            float gx = pr[0] - qv[0];
            float gy = pr[1] - qv[1];
            float gz = pr[2] - qv[2];
            half2v h2; h2[0] = (_Float16)gx; h2[1] = (_Float16)gy;
            *(half2v*)&G[ni * K1P + 64] = h2;
            G[ni * K1P + 66] = (_Float16)gz;
        }
    }
    __syncthreads();   // G, sW, Lb ready

    const int myrow = wv * 16 + c;    // this lane's neighbor row

    // ---- layer 1: h1^T[64 x 16] = W1t(64x96) x G^T, K=96 (3 steps) ----
    {
        floatx4 acc[4] = {};
#pragma unroll
        for (int ks = 0; ks < 3; ++ks) {
            const int k0 = ks * 32;
            half8v bf = *(const half8v*)&G[myrow * K1P + k0 + q * 8];
#pragma unroll
            for (int mt = 0; mt < 4; ++mt) {
                half8v af = *(const half8v*)&sW[(mt * 16 + c) * K1P + k0 + q * 8];
                acc[mt] = __builtin_amdgcn_mfma_f32_16x16x32_f16(af, bf, acc[mt], 0, 0, 0);
            }
        }
#pragma unroll
        for (int mt = 0; mt < 4; ++mt) {
            float4 bb = *(const float4*)&Lb[mt * 16 + q * 4];
            half4v h;
            h[0] = (_Float16)fmaxf(acc[mt][0] + bb.x, 0.f);
            h[1] = (_Float16)fmaxf(acc[mt][1] + bb.y, 0.f);
            h[2] = (_Float16)fmaxf(acc[mt][2] + bb.z, 0.f);
            h[3] = (_Float16)fmaxf(acc[mt][3] + bb.w, 0.f);
            *(half4v*)&H1[myrow * K2P + mt * 16 + q * 4] = h;
        }
    }
    // wave-private region: no block barrier needed (compiler emits lgkmcnt waits)

    // ---- layer 2: h2^T = W2t(64x64) x h1^T, K=64 (2 steps) ----
    {
        floatx4 acc[4] = {};
#pragma unroll
        for (int ks = 0; ks < 2; ++ks) {
            const int k0 = ks * 32;
            half8v bf = *(const half8v*)&H1[myrow * K2P + k0 + q * 8];
#pragma unroll
            for (int mt = 0; mt < 4; ++mt) {
                half8v af = *(const half8v*)&sW[6656 + (mt * 16 + c) * K2P + k0 + q * 8];
                acc[mt] = __builtin_amdgcn_mfma_f32_16x16x32_f16(af, bf, acc[mt], 0, 0, 0);
            }
        }
#pragma unroll
        for (int mt = 0; mt < 4; ++mt) {
            float4 bb = *(const float4*)&Lb[64 + mt * 16 + q * 4];
            half4v h;
            h[0] = (_Float16)fmaxf(acc[mt][0] + bb.x, 0.f);
            h[1] = (_Float16)fmaxf(acc[mt][1] + bb.y, 0.f);
            h[2] = (_Float16)fmaxf(acc[mt][2] + bb.z, 0.f);
            h[3] = (_Float16)fmaxf(acc[mt][3] + bb.w, 0.f);
            *(half4v*)&H2[myrow * K2P + mt * 16 + q * 4] = h;
        }
    }

    // ---- layer 3: h3^T[128 x 16] = W3t(128x64) x h2^T, K=64, +b3, mask, max ----
    {
        floatx4 acc[8] = {};
#pragma unroll
        for (int ks = 0; ks < 2; ++ks) {
            const int k0 = ks * 32;
            half8v bf = *(const half8v*)&H2[myrow * K2P + k0 + q * 8];
#pragma unroll
            for (int mt = 0; mt < 8; ++mt) {
                half8v af = *(const half8v*)&sW[11264 + (mt * 16 + c) * K2P + k0 + q * 8];
                acc[mt] = __builtin_amdgcn_mfma_f32_16x16x32_f16(af, bf, acc[mt], 0, 0, 0);
            }
        }
        const bool valid = nbr_s[myrow] >= 0;
        float pm[8][4];
#pragma unroll
        for (int mt = 0; mt < 8; ++mt) {
            float4 bb = *(const float4*)&Lb[128 + mt * 16 + q * 4];
            pm[mt][0] = valid ? (acc[mt][0] + bb.x) : 0.f;
            pm[mt][1] = valid ? (acc[mt][1] + bb.y) : 0.f;
            pm[mt][2] = valid ? (acc[mt][2] + bb.z) : 0.f;
            pm[mt][3] = valid ? (acc[mt][3] + bb.w) : 0.f;
        }
        // butterfly max over the 16 neighbor-cols (lane bits 0..3)
#pragma unroll
        for (int off = 1; off < 16; off <<= 1) {
#pragma unroll
            for (int mt = 0; mt < 8; ++mt)
#pragma unroll
                for (int r = 0; r < 4; ++r)
                    pm[mt][r] = fmaxf(pm[mt][r], __shfl_xor(pm[mt][r], off));
        }
        if (c == 0) {
#pragma unroll
            for (int mt = 0; mt < 8; ++mt) {
                float4 v = make_float4(pm[mt][0], pm[mt][1], pm[mt][2], pm[mt][3]);
                *(float4*)&CW[wv * NCO + mt * 16 + q * 4] = v;
            }
        }
    }
    __syncthreads();
    if (tid < NCO) {
        float m0 = fmaxf(CW[tid], CW[NCO + tid]);
        float m1 = fmaxf(CW[2 * NCO + tid], CW[3 * NCO + tid]);
        out[(size_t)bs * NCO + tid] = fmaxf(m0, m1);
    }
}

extern "C" void kernel_launch(void* const* d_in, const int* in_sizes, int n_in,
                              void* d_out, int out_size, void* d_ws, size_t ws_size,
                              hipStream_t stream) {
    const float* x   = (const float*)d_in[0];
    const float* pos = (const float*)d_in[1];
    const float* W1  = (const float*)d_in[2];
    const float* b1  = (const float*)d_in[3];
    const float* W2  = (const float*)d_in[4];
    const float* b2  = (const float*)d_in[5];
    const float* W3  = (const float*)d_in[6];
    const float* b3  = (const float*)d_in[7];

    float* out0 = (float*)d_out;                       // [B,S,128]
    float* nxyz = out0 + (size_t)NB * NS * NCO;        // [B,S,3]
    short* bidx = (short*)d_ws;                        // [B,S,K] int16 = 1 MB
    _Float16* wtp = (_Float16*)((char*)d_ws + (size_t)NB * NS * NK * sizeof(short));

    wt_kernel<<<256, 64, 0, stream>>>(W1, W2, W3, wtp);
    fps_kernel<<<NB, FPS_T, 0, stream>>>(pos, nxyz);
    ballq_kernel<<<(NB * NS) / 4, 256, 0, stream>>>(pos, nxyz, bidx);
    mlp_kernel<<<NB * NS, 256, 0, stream>>>(x, pos, b1, b2, b3,
                                            nxyz, bidx, wtp, out0);
}